// Round 8
// baseline (118.417 us; speedup 1.0000x reference)
//
#include <hip/hip_runtime.h>
#include <cstdint>

#define BB   16
#define NN   1024
#define FIN  128
#define FOUT 64
#define ALPHA_S 0.2f
#define LOG2E 1.44269504f

typedef float    f32x4 __attribute__((ext_vector_type(4)));
typedef _Float16 half8 __attribute__((ext_vector_type(8)));
typedef _Float16 half4 __attribute__((ext_vector_type(4)));
typedef __fp16   pk2   __attribute__((ext_vector_type(2)));
typedef __fp16   pk4   __attribute__((ext_vector_type(4)));
typedef __fp16   pk8   __attribute__((ext_vector_type(8)));

__device__ __forceinline__ float fast_exp2(float x){
  float r; asm("v_exp_f32 %0, %1" : "=v"(r) : "v"(x)); return r;
}

// ---------------------------------------------------------------------------
// Kernel 1 (MFMA): h = inp @ W, f16 hi/lo 3-term MFMA (rel err ~2^-22).
// Also streams the adj rows for its 16-row tile and emits the adj>0 bitmask
// (2xu32/lane) to workspace.  Load order: inp (8xfloat4) -> W (32 dword) ->
// adj (16 int4, YOUNGEST).  vmcnt is FIFO, so the MFMA section's waits on
// inp/W leave the adj burst in flight -- the 67 MB adj stream rides under
// k_proj's compute and k_attn only reads the 2 MB mask.
// NOTE: i0 here is the GLOBAL row (= b*1024 + j0); adj row index is
// (i0 + m16) * NN  (R7 bug: added b*NN again -> OOB -> abort).
// Mask layout: msk[blk*256 + t] = {lo,hi}, bit u of byte kk corresponds to
// col w*256 + kk*32 + g*8 + u  (identical to R5 pass 1).
// s1 = (h.a1)*log2e, s2 = (h.a2)*log2e; hT layout hT[b][j>>5][f][j&31].
// ---------------------------------------------------------------------------
__global__ __launch_bounds__(256) void k_proj(const float* __restrict__ inp,
                                              const float* __restrict__ W,
                                              const float* __restrict__ a,
                                              const int* __restrict__ adj,
                                              _Float16* __restrict__ hT,
                                              float* __restrict__ s1,
                                              float* __restrict__ s2,
                                              uint2* __restrict__ msk){
  __shared__ float red1[4][16];
  __shared__ float red2[4][16];
  const int t = threadIdx.x;
  const int w = t >> 6, lane = t & 63;
  const int m16 = lane & 15, g = lane >> 4;
  const int i0 = blockIdx.x * 16;          // GLOBAL row tile (16 rows)
  const int b  = i0 >> 10;
  const int j0 = i0 & 1023;
  const int c0 = w * 16;                   // this wave's col tile

  // ---- 1) inp loads upfront (8 float4) ----
  const float* arow_i = inp + (size_t)(i0 + m16) * FIN;
  float4 iv0[4], iv1[4];
  #pragma unroll
  for (int kk = 0; kk < 4; ++kk){
    iv0[kk] = *(const float4*)(arow_i + kk * 32 + g * 8);
    iv1[kk] = *(const float4*)(arow_i + kk * 32 + g * 8 + 4);
  }
  // ---- 2) W loads upfront (32 dword, L1/L2-hot) ----
  float wv[4][8];
  #pragma unroll
  for (int kk = 0; kk < 4; ++kk){
    #pragma unroll
    for (int j = 0; j < 8; ++j)
      wv[kk][j] = W[(kk * 32 + g * 8 + j) * FOUT + c0 + m16];
  }
  // ---- 3) adj burst LAST (16 int4) -- stays outstanding through MFMAs ----
  const int* arow_a = adj + (size_t)(i0 + m16) * NN + w * 256 + g * 8;
  int4 A0[8], A1[8];
  #pragma unroll
  for (int kk = 0; kk < 8; ++kk){
    A0[kk] = *(const int4*)(arow_a + kk * 32);
    A1[kk] = *(const int4*)(arow_a + kk * 32 + 4);
  }

  // ---- 4) fragments + MFMA (consumes only inp/W: older than adj) ----
  f32x4 acc = {0.f, 0.f, 0.f, 0.f};
  #pragma unroll
  for (int kk = 0; kk < 4; ++kk){
    const float av[8] = {iv0[kk].x, iv0[kk].y, iv0[kk].z, iv0[kk].w,
                         iv1[kk].x, iv1[kk].y, iv1[kk].z, iv1[kk].w};
    half8 ah, al, bh, bl;
    #pragma unroll
    for (int j = 0; j < 8; ++j){
      _Float16 h = (_Float16)av[j];
      ah[j] = h;
      al[j] = (_Float16)(av[j] - (float)h);
      _Float16 hw = (_Float16)wv[kk][j];
      bh[j] = hw;
      bl[j] = (_Float16)(wv[kk][j] - (float)hw);
    }
    acc = __builtin_amdgcn_mfma_f32_16x16x32_f16(ah, bh, acc, 0, 0, 0);
    acc = __builtin_amdgcn_mfma_f32_16x16x32_f16(ah, bl, acc, 0, 0, 0);
    acc = __builtin_amdgcn_mfma_f32_16x16x32_f16(al, bh, acc, 0, 0, 0);
  }

  // ---- s1/s2 partials: sum over this wave's 16 cols, rows g*4+q ----
  const float a1c = a[c0 + m16];
  const float a2c = a[FOUT + c0 + m16];
  f32x4 p1, p2;
  #pragma unroll
  for (int q = 0; q < 4; ++q){ p1[q] = acc[q] * a1c; p2[q] = acc[q] * a2c; }
  #pragma unroll
  for (int off = 1; off < 16; off <<= 1){
    #pragma unroll
    for (int q = 0; q < 4; ++q){
      p1[q] += __shfl_xor(p1[q], off, 64);
      p2[q] += __shfl_xor(p2[q], off, 64);
    }
  }
  if (m16 == 0){
    #pragma unroll
    for (int q = 0; q < 4; ++q){
      red1[w][g * 4 + q] = p1[q];
      red2[w][g * 4 + q] = p2[q];
    }
  }

  // ---- hT store (hi only): f = c0+m16, j = i0 + g*4 + q ----
  half4 hv;
  #pragma unroll
  for (int q = 0; q < 4; ++q) hv[q] = (_Float16)acc[q];
  size_t idx = (size_t)b * 65536 + (size_t)(j0 >> 5) * 2048
             + (size_t)(c0 + m16) * 32 + (size_t)(j0 & 31) + (size_t)g * 4;
  *(half4*)(hT + idx) = hv;

  __syncthreads();
  if (t < 16){
    s1[i0 + t] = (red1[0][t] + red1[1][t] + red1[2][t] + red1[3][t]) * LOG2E;
    s2[i0 + t] = (red2[0][t] + red2[1][t] + red2[2][t] + red2[3][t]) * LOG2E;
  }

  // ---- 5) adj bitmask pack + store (adj burst has long landed) ----
  unsigned mask_lo = 0u, mask_hi = 0u;
  #pragma unroll
  for (int kk = 0; kk < 8; ++kk){
    unsigned bits = 0u;
    bits |= (A0[kk].x > 0) ? 1u   : 0u;
    bits |= (A0[kk].y > 0) ? 2u   : 0u;
    bits |= (A0[kk].z > 0) ? 4u   : 0u;
    bits |= (A0[kk].w > 0) ? 8u   : 0u;
    bits |= (A1[kk].x > 0) ? 16u  : 0u;
    bits |= (A1[kk].y > 0) ? 32u  : 0u;
    bits |= (A1[kk].z > 0) ? 64u  : 0u;
    bits |= (A1[kk].w > 0) ? 128u : 0u;
    if (kk < 4) mask_lo |= bits << (kk * 8);
    else        mask_hi |= bits << ((kk - 4) * 8);
  }
  msk[(size_t)blockIdx.x * 256 + t] = make_uint2(mask_lo, mask_hi);
}

// ---------------------------------------------------------------------------
// Kernel 2: fused GAT attention, mask-fed (no adj stream -- 2 MB mask read
// instead of 67 MB).  Structure otherwise identical to R5 (best verified):
// barrier-free main body, wave-local masked max, single epilogue barrier,
// flash-style cross-wave merge.
// ---------------------------------------------------------------------------
__global__ __launch_bounds__(256, 4) void k_attn(const uint2* __restrict__ msk,
                                                 const _Float16* __restrict__ hT,
                                                 const float* __restrict__ s1,
                                                 const float* __restrict__ s2,
                                                 float* __restrict__ out){
  __shared__ float s2_s[NN];            // 4 KB
  __shared__ float redmax[4][16];
  __shared__ float redl[4][16];
  __shared__ float csum[4][1088];       // 4 x (16 rows x 68-pad) ~17 KB

  const int t = threadIdx.x;
  const int w = t >> 6, lane = t & 63;
  const int m16 = lane & 15, g = lane >> 4;
  const int b  = blockIdx.x >> 6;
  const int i0 = (blockIdx.x & 63) * 16;
  const int jb = w * 256;

  // stage this wave's s2 chunk (wave-internal lgkmcnt ordering; only this
  // wave reads its chunk, so no barrier needed before the LDS reads)
  *(float4*)&s2_s[jb + lane * 4] = *(const float4*)(s2 + b * NN + jb + lane * 4);

  // mask (written by k_proj block blockIdx.x, same thread) + s1
  const uint2 mk  = msk[(size_t)blockIdx.x * 256 + t];
  const float s1i = s1[b * NN + i0 + m16];

  // ---- pass 1: wave-local masked max of s2 from mask bits ----
  float mxp = -3.0e38f;
  #pragma unroll
  for (int kk = 0; kk < 8; ++kk){
    float4 sA = *(const float4*)&s2_s[jb + kk * 32 + g * 8];
    float4 sB = *(const float4*)&s2_s[jb + kk * 32 + g * 8 + 4];
    const unsigned bits = (kk < 4) ? (mk.x >> (kk * 8)) : (mk.y >> ((kk - 4) * 8));
    mxp = fmaxf(mxp, (bits & 1u)   ? sA.x : -3.0e38f);
    mxp = fmaxf(mxp, (bits & 2u)   ? sA.y : -3.0e38f);
    mxp = fmaxf(mxp, (bits & 4u)   ? sA.z : -3.0e38f);
    mxp = fmaxf(mxp, (bits & 8u)   ? sA.w : -3.0e38f);
    mxp = fmaxf(mxp, (bits & 16u)  ? sB.x : -3.0e38f);
    mxp = fmaxf(mxp, (bits & 32u)  ? sB.y : -3.0e38f);
    mxp = fmaxf(mxp, (bits & 64u)  ? sB.z : -3.0e38f);
    mxp = fmaxf(mxp, (bits & 128u) ? sB.w : -3.0e38f);
  }

  // wave-local row max across the 4 lanes sharing m16 (no cross-wave barrier)
  mxp = fmaxf(mxp, __shfl_xor(mxp, 16, 64));
  mxp = fmaxf(mxp, __shfl_xor(mxp, 32, 64));
  mxp = fmaxf(mxp, -1.0e30f);                 // empty-row safe clamp
  const float xm   = s1i + mxp;
  const float mrow = fmaxf(xm, ALPHA_S * xm); // wave-local max of leaky (log2 dom)
  if (g == 0) redmax[w][m16] = mrow;
  const float s1m = s1i - mrow;
  const float c2  = ALPHA_S * s1i - mrow;

  // ---- pass 2: p from mask + LDS s2 -> 4 col-tile MFMAs (hi only) ----
  f32x4 acc0 = {0,0,0,0}, acc1 = {0,0,0,0}, acc2 = {0,0,0,0}, acc3 = {0,0,0,0};
  float psum = 0.f;
  const _Float16* bhp = hT + (size_t)b * 65536 + (size_t)(w * 8) * 2048
                      + (size_t)m16 * 32 + (size_t)g * 8;

  #pragma unroll
  for (int kk = 0; kk < 8; ++kk){
    float4 sA = *(const float4*)&s2_s[jb + kk * 32 + g * 8];
    float4 sB = *(const float4*)&s2_s[jb + kk * 32 + g * 8 + 4];
    const unsigned bits = (kk < 4) ? (mk.x >> (kk * 8)) : (mk.y >> ((kk - 4) * 8));
    const float sv[8] = {sA.x, sA.y, sA.z, sA.w, sB.x, sB.y, sB.z, sB.w};
    float p[8];
    #pragma unroll
    for (int u = 0; u < 8; ++u){
      float e = fast_exp2(fmaxf(s1m + sv[u], fmaf(ALPHA_S, sv[u], c2)));
      p[u] = ((bits >> u) & 1u) ? e : 0.0f;
    }
    psum += ((p[0] + p[1]) + (p[2] + p[3])) + ((p[4] + p[5]) + (p[6] + p[7]));

    pk2 q0 = __builtin_amdgcn_cvt_pkrtz(p[0], p[1]);
    pk2 q1 = __builtin_amdgcn_cvt_pkrtz(p[2], p[3]);
    pk2 q2 = __builtin_amdgcn_cvt_pkrtz(p[4], p[5]);
    pk2 q3 = __builtin_amdgcn_cvt_pkrtz(p[6], p[7]);
    pk4 l0 = __builtin_shufflevector(q0, q1, 0, 1, 2, 3);
    pk4 l1 = __builtin_shufflevector(q2, q3, 0, 1, 2, 3);
    half8 af = __builtin_bit_cast(half8,
                 __builtin_shufflevector(l0, l1, 0, 1, 2, 3, 4, 5, 6, 7));

    half8 b0 = *(const half8*)(bhp + kk * 2048);
    half8 b1 = *(const half8*)(bhp + kk * 2048 + 512);
    half8 b2 = *(const half8*)(bhp + kk * 2048 + 1024);
    half8 b3 = *(const half8*)(bhp + kk * 2048 + 1536);
    acc0 = __builtin_amdgcn_mfma_f32_16x16x32_f16(af, b0, acc0, 0, 0, 0);
    acc1 = __builtin_amdgcn_mfma_f32_16x16x32_f16(af, b1, acc1, 0, 0, 0);
    acc2 = __builtin_amdgcn_mfma_f32_16x16x32_f16(af, b2, acc2, 0, 0, 0);
    acc3 = __builtin_amdgcn_mfma_f32_16x16x32_f16(af, b3, acc3, 0, 0, 0);
  }

  // ---- epilogue: single barrier; flash-style cross-wave merge ----
  psum += __shfl_xor(psum, 16, 64);
  psum += __shfl_xor(psum, 32, 64);
  if (g == 0) redl[w][m16] = psum;

  #pragma unroll
  for (int q = 0; q < 4; ++q){                 // C: row = g*4+q, col = c*16+m16
    csum[w][(g * 4 + q) * 68 +  0 + m16] = acc0[q];
    csum[w][(g * 4 + q) * 68 + 16 + m16] = acc1[q];
    csum[w][(g * 4 + q) * 68 + 32 + m16] = acc2[q];
    csum[w][(g * 4 + q) * 68 + 48 + m16] = acc3[q];
  }
  __syncthreads();

  const int r  = t >> 4;                       // 0..15
  const int c4 = (t & 15) * 4;                 // 0..60
  const float m0 = redmax[0][r], m1 = redmax[1][r];
  const float m2 = redmax[2][r], m3 = redmax[3][r];
  const float mg = fmaxf(fmaxf(m0, m1), fmaxf(m2, m3));
  const float f0 = fast_exp2(m0 - mg), f1 = fast_exp2(m1 - mg);
  const float f2 = fast_exp2(m2 - mg), f3 = fast_exp2(m3 - mg);

  f32x4 c0v = *(const f32x4*)&csum[0][r * 68 + c4];
  f32x4 c1v = *(const f32x4*)&csum[1][r * 68 + c4];
  f32x4 c2v = *(const f32x4*)&csum[2][r * 68 + c4];
  f32x4 c3v = *(const f32x4*)&csum[3][r * 68 + c4];
  f32x4 sum;
  #pragma unroll
  for (int u = 0; u < 4; ++u)
    sum[u] = c0v[u] * f0 + c1v[u] * f1 + c2v[u] * f2 + c3v[u] * f3;

  const float l = redl[0][r] * f0 + redl[1][r] * f1
                + redl[2][r] * f2 + redl[3][r] * f3;
  const float linv = (l > 0.f) ? __builtin_amdgcn_rcpf(l) : 0.f;
  f32x4 o;
  #pragma unroll
  for (int u = 0; u < 4; ++u){
    float v = sum[u] * linv;
    o[u] = v > 0.f ? v : __expf(v) - 1.0f;     // ELU (alpha=1)
  }
  *(f32x4*)(out + ((size_t)(b * NN + i0 + r)) * FOUT + c4) = o;
}

extern "C" void kernel_launch(void* const* d_in, const int* in_sizes, int n_in,
                              void* d_out, int out_size, void* d_ws, size_t ws_size,
                              hipStream_t stream) {
  (void)in_sizes; (void)n_in; (void)out_size; (void)ws_size;
  const float* inp = (const float*)d_in[0];   // (16,1024,128) fp32
  const int*   adj = (const int*)d_in[1];     // (16,1024,1024) int32
  const float* W   = (const float*)d_in[2];   // (128,64) fp32
  const float* a   = (const float*)d_in[3];   // (128,1) fp32
  float* outp = (float*)d_out;                // (16,1024,64) fp32

  _Float16* hT = (_Float16*)d_ws;                      // 2 MB (hi only)
  float* s1 = (float*)(hT + (size_t)BB * 65536);       // 64 KB
  float* s2 = s1 + BB * NN;                            // 64 KB
  uint2* msk = (uint2*)(s2 + BB * NN);                 // 2 MB bitmask

  k_proj<<<BB * NN / 16, 256, 0, stream>>>(inp, W, a, adj, hT, s1, s2, msk);
  k_attn<<<BB * (NN / 16), 256, 0, stream>>>(msk, hT, s1, s2, outp);
}

// Round 9
// 115.648 us; speedup vs baseline: 1.0239x; 1.0239x over previous
//
#include <hip/hip_runtime.h>
#include <cstdint>

#define BB   16
#define NN   1024
#define FIN  128
#define FOUT 64
#define ALPHA_S 0.2f
#define LOG2E 1.44269504f

typedef float    f32x4 __attribute__((ext_vector_type(4)));
typedef _Float16 half8 __attribute__((ext_vector_type(8)));
typedef _Float16 half4 __attribute__((ext_vector_type(4)));
typedef __fp16   pk2   __attribute__((ext_vector_type(2)));
typedef __fp16   pk4   __attribute__((ext_vector_type(4)));
typedef __fp16   pk8   __attribute__((ext_vector_type(8)));

__device__ __forceinline__ float fast_exp2(float x){
  float r; asm("v_exp_f32 %0, %1" : "=v"(r) : "v"(x)); return r;
}

// ---------------------------------------------------------------------------
// Kernel 1 (MFMA): h = inp @ W via f16 hi/lo 3-term MFMA (rel err ~2^-22);
// s1 = (h.a1)*log2e, s2 = (h.a2)*log2e  (log2-domain fold for k_attn's exp2);
// hT (f16, hi only) in layout hT[b][j>>5][f][j&31].
// [R9 = exact revert to R5: best verified 114.6 us.  R6 (W amortization)
//  nulled; R8 (adj overlap into k_proj) regressed +3.8 us -- the held adj
//  burst's 64 VGPRs cost more occupancy than the overlap gained.]
// ---------------------------------------------------------------------------
__global__ __launch_bounds__(256) void k_proj(const float* __restrict__ inp,
                                              const float* __restrict__ W,
                                              const float* __restrict__ a,
                                              _Float16* __restrict__ hT,
                                              float* __restrict__ s1,
                                              float* __restrict__ s2){
  __shared__ float red1[4][16];
  __shared__ float red2[4][16];
  const int t = threadIdx.x;
  const int w = t >> 6, lane = t & 63;
  const int m16 = lane & 15, g = lane >> 4;
  const int i0 = blockIdx.x * 16;          // global row tile (16 rows)
  const int b  = i0 >> 10;
  const int j0 = i0 & 1023;
  const int c0 = w * 16;                   // this wave's col tile

  const float* arow = inp + (size_t)(i0 + m16) * FIN;

  f32x4 acc = {0.f, 0.f, 0.f, 0.f};
  #pragma unroll
  for (int kk = 0; kk < 4; ++kk){
    const int kbase = kk * 32 + g * 8;
    float4 av0 = *(const float4*)(arow + kbase);
    float4 av1 = *(const float4*)(arow + kbase + 4);
    const float av[8] = {av0.x, av0.y, av0.z, av0.w, av1.x, av1.y, av1.z, av1.w};
    half8 ah, al;
    #pragma unroll
    for (int j = 0; j < 8; ++j){
      _Float16 h = (_Float16)av[j];
      ah[j] = h;
      al[j] = (_Float16)(av[j] - (float)h);
    }
    half8 bh, bl;
    #pragma unroll
    for (int j = 0; j < 8; ++j){
      float wv = W[(kbase + j) * FOUT + c0 + m16];   // L1-hot (W = 32 KB)
      _Float16 h = (_Float16)wv;
      bh[j] = h;
      bl[j] = (_Float16)(wv - (float)h);
    }
    acc = __builtin_amdgcn_mfma_f32_16x16x32_f16(ah, bh, acc, 0, 0, 0);
    acc = __builtin_amdgcn_mfma_f32_16x16x32_f16(ah, bl, acc, 0, 0, 0);
    acc = __builtin_amdgcn_mfma_f32_16x16x32_f16(al, bh, acc, 0, 0, 0);
  }

  // ---- s1/s2 partials: sum over this wave's 16 cols, rows g*4+q ----
  const float a1c = a[c0 + m16];
  const float a2c = a[FOUT + c0 + m16];
  f32x4 p1, p2;
  #pragma unroll
  for (int q = 0; q < 4; ++q){ p1[q] = acc[q] * a1c; p2[q] = acc[q] * a2c; }
  #pragma unroll
  for (int off = 1; off < 16; off <<= 1){
    #pragma unroll
    for (int q = 0; q < 4; ++q){
      p1[q] += __shfl_xor(p1[q], off, 64);
      p2[q] += __shfl_xor(p2[q], off, 64);
    }
  }
  if (m16 == 0){
    #pragma unroll
    for (int q = 0; q < 4; ++q){
      red1[w][g * 4 + q] = p1[q];
      red2[w][g * 4 + q] = p2[q];
    }
  }

  // ---- hT store (hi only): f = c0+m16, j = i0 + g*4 + q ----
  half4 hv;
  #pragma unroll
  for (int q = 0; q < 4; ++q) hv[q] = (_Float16)acc[q];
  size_t idx = (size_t)b * 65536 + (size_t)(j0 >> 5) * 2048
             + (size_t)(c0 + m16) * 32 + (size_t)(j0 & 31) + (size_t)g * 4;
  *(half4*)(hT + idx) = hv;

  __syncthreads();
  if (t < 16){
    s1[i0 + t] = (red1[0][t] + red1[1][t] + red1[2][t] + red1[3][t]) * LOG2E;
    s2[i0 + t] = (red2[0][t] + red2[1][t] + red2[2][t] + red2[3][t]) * LOG2E;
  }
}

// ---------------------------------------------------------------------------
// Kernel 2: fused GAT attention, barrier-free main body, low-VGPR variant.
// 1024 blocks x 256 thr = EXACTLY 4 blocks/CU resident (one wavefront-round,
// no tail) under __launch_bounds__(256,4) -> <=128 VGPR, 16 waves/CU.
// Wave w owns j-range [w*256, w*256+256).  Pass 1: 16-int4 adj burst (full
// MLP, proven R2 structure) -> 2-reg bitmask + wave-LOCAL masked max of s2
// (read from LDS).  Pass 2: re-reads s2 from LDS (saves 48 VGPR vs sm[64]),
// p = bit ? exp2(max(s1m+sv, fma(a,sv,c2))) : 0, cvt_pkrtz -> A-frag,
// 4 col-tile MFMAs per kk.  Single barrier; epilogue merges waves
// flash-style by output row r (exact).
// ---------------------------------------------------------------------------
__global__ __launch_bounds__(256, 4) void k_attn(const int* __restrict__ adj,
                                                 const _Float16* __restrict__ hT,
                                                 const float* __restrict__ s1,
                                                 const float* __restrict__ s2,
                                                 float* __restrict__ out){
  __shared__ float s2_s[NN];            // 4 KB
  __shared__ float redmax[4][16];
  __shared__ float redl[4][16];
  __shared__ float csum[4][1088];       // 4 x (16 rows x 68-pad) ~17 KB

  const int t = threadIdx.x;
  const int w = t >> 6, lane = t & 63;
  const int m16 = lane & 15, g = lane >> 4;
  const int b  = blockIdx.x >> 6;
  const int i0 = (blockIdx.x & 63) * 16;
  const int jb = w * 256;

  // stage this wave's s2 chunk (wave-internal lgkmcnt ordering; only this
  // wave reads its chunk, so no barrier needed before the LDS reads)
  *(float4*)&s2_s[jb + lane * 4] = *(const float4*)(s2 + b * NN + jb + lane * 4);

  // ---- adj burst: 16 int4 loads in flight; row i0+m16, cols jb+kk*32+g*8 ----
  const int* arow = adj + ((size_t)(b * NN + i0 + m16)) * NN + jb + g * 8;
  int4 A0[8], A1[8];
  #pragma unroll
  for (int kk = 0; kk < 8; ++kk){
    A0[kk] = *(const int4*)(arow + kk * 32);
    A1[kk] = *(const int4*)(arow + kk * 32 + 4);
  }

  const float s1i = s1[b * NN + i0 + m16];

  // ---- pass 1: bitmask (2 regs) + wave-local masked max of s2 ----
  unsigned mask_lo = 0u, mask_hi = 0u;
  float mxp = -3.0e38f;
  #pragma unroll
  for (int kk = 0; kk < 8; ++kk){
    float4 sA = *(const float4*)&s2_s[jb + kk * 32 + g * 8];
    float4 sB = *(const float4*)&s2_s[jb + kk * 32 + g * 8 + 4];
    unsigned bits = 0u;
    bits |= (A0[kk].x > 0) ? 1u   : 0u;  mxp = fmaxf(mxp, A0[kk].x > 0 ? sA.x : -3.0e38f);
    bits |= (A0[kk].y > 0) ? 2u   : 0u;  mxp = fmaxf(mxp, A0[kk].y > 0 ? sA.y : -3.0e38f);
    bits |= (A0[kk].z > 0) ? 4u   : 0u;  mxp = fmaxf(mxp, A0[kk].z > 0 ? sA.z : -3.0e38f);
    bits |= (A0[kk].w > 0) ? 8u   : 0u;  mxp = fmaxf(mxp, A0[kk].w > 0 ? sA.w : -3.0e38f);
    bits |= (A1[kk].x > 0) ? 16u  : 0u;  mxp = fmaxf(mxp, A1[kk].x > 0 ? sB.x : -3.0e38f);
    bits |= (A1[kk].y > 0) ? 32u  : 0u;  mxp = fmaxf(mxp, A1[kk].y > 0 ? sB.y : -3.0e38f);
    bits |= (A1[kk].z > 0) ? 64u  : 0u;  mxp = fmaxf(mxp, A1[kk].z > 0 ? sB.z : -3.0e38f);
    bits |= (A1[kk].w > 0) ? 128u : 0u;  mxp = fmaxf(mxp, A1[kk].w > 0 ? sB.w : -3.0e38f);
    if (kk < 4) mask_lo |= bits << (kk * 8);
    else        mask_hi |= bits << ((kk - 4) * 8);
  }

  // wave-local row max across the 4 lanes sharing m16 (no cross-wave barrier)
  mxp = fmaxf(mxp, __shfl_xor(mxp, 16, 64));
  mxp = fmaxf(mxp, __shfl_xor(mxp, 32, 64));
  mxp = fmaxf(mxp, -1.0e30f);                 // empty-row safe clamp
  const float xm   = s1i + mxp;
  const float mrow = fmaxf(xm, ALPHA_S * xm); // wave-local max of leaky (log2 dom)
  if (g == 0) redmax[w][m16] = mrow;
  const float s1m = s1i - mrow;
  const float c2  = ALPHA_S * s1i - mrow;

  // ---- pass 2: p from mask + LDS s2 -> 4 col-tile MFMAs (hi only) ----
  f32x4 acc0 = {0,0,0,0}, acc1 = {0,0,0,0}, acc2 = {0,0,0,0}, acc3 = {0,0,0,0};
  float psum = 0.f;
  const _Float16* bhp = hT + (size_t)b * 65536 + (size_t)(w * 8) * 2048
                      + (size_t)m16 * 32 + (size_t)g * 8;

  #pragma unroll
  for (int kk = 0; kk < 8; ++kk){
    float4 sA = *(const float4*)&s2_s[jb + kk * 32 + g * 8];
    float4 sB = *(const float4*)&s2_s[jb + kk * 32 + g * 8 + 4];
    const unsigned bits = (kk < 4) ? (mask_lo >> (kk * 8)) : (mask_hi >> ((kk - 4) * 8));
    const float sv[8] = {sA.x, sA.y, sA.z, sA.w, sB.x, sB.y, sB.z, sB.w};
    float p[8];
    #pragma unroll
    for (int u = 0; u < 8; ++u){
      float e = fast_exp2(fmaxf(s1m + sv[u], fmaf(ALPHA_S, sv[u], c2)));
      p[u] = ((bits >> u) & 1u) ? e : 0.0f;
    }
    psum += ((p[0] + p[1]) + (p[2] + p[3])) + ((p[4] + p[5]) + (p[6] + p[7]));

    pk2 q0 = __builtin_amdgcn_cvt_pkrtz(p[0], p[1]);
    pk2 q1 = __builtin_amdgcn_cvt_pkrtz(p[2], p[3]);
    pk2 q2 = __builtin_amdgcn_cvt_pkrtz(p[4], p[5]);
    pk2 q3 = __builtin_amdgcn_cvt_pkrtz(p[6], p[7]);
    pk4 l0 = __builtin_shufflevector(q0, q1, 0, 1, 2, 3);
    pk4 l1 = __builtin_shufflevector(q2, q3, 0, 1, 2, 3);
    half8 af = __builtin_bit_cast(half8,
                 __builtin_shufflevector(l0, l1, 0, 1, 2, 3, 4, 5, 6, 7));

    half8 b0 = *(const half8*)(bhp + kk * 2048);
    half8 b1 = *(const half8*)(bhp + kk * 2048 + 512);
    half8 b2 = *(const half8*)(bhp + kk * 2048 + 1024);
    half8 b3 = *(const half8*)(bhp + kk * 2048 + 1536);
    acc0 = __builtin_amdgcn_mfma_f32_16x16x32_f16(af, b0, acc0, 0, 0, 0);
    acc1 = __builtin_amdgcn_mfma_f32_16x16x32_f16(af, b1, acc1, 0, 0, 0);
    acc2 = __builtin_amdgcn_mfma_f32_16x16x32_f16(af, b2, acc2, 0, 0, 0);
    acc3 = __builtin_amdgcn_mfma_f32_16x16x32_f16(af, b3, acc3, 0, 0, 0);
  }

  // ---- epilogue: single barrier; flash-style cross-wave merge ----
  psum += __shfl_xor(psum, 16, 64);
  psum += __shfl_xor(psum, 32, 64);
  if (g == 0) redl[w][m16] = psum;

  #pragma unroll
  for (int q = 0; q < 4; ++q){                 // C: row = g*4+q, col = c*16+m16
    csum[w][(g * 4 + q) * 68 +  0 + m16] = acc0[q];
    csum[w][(g * 4 + q) * 68 + 16 + m16] = acc1[q];
    csum[w][(g * 4 + q) * 68 + 32 + m16] = acc2[q];
    csum[w][(g * 4 + q) * 68 + 48 + m16] = acc3[q];
  }
  __syncthreads();

  const int r  = t >> 4;                       // 0..15
  const int c4 = (t & 15) * 4;                 // 0..60
  const float m0 = redmax[0][r], m1 = redmax[1][r];
  const float m2 = redmax[2][r], m3 = redmax[3][r];
  const float mg = fmaxf(fmaxf(m0, m1), fmaxf(m2, m3));
  const float f0 = fast_exp2(m0 - mg), f1 = fast_exp2(m1 - mg);
  const float f2 = fast_exp2(m2 - mg), f3 = fast_exp2(m3 - mg);

  f32x4 c0v = *(const f32x4*)&csum[0][r * 68 + c4];
  f32x4 c1v = *(const f32x4*)&csum[1][r * 68 + c4];
  f32x4 c2v = *(const f32x4*)&csum[2][r * 68 + c4];
  f32x4 c3v = *(const f32x4*)&csum[3][r * 68 + c4];
  f32x4 sum;
  #pragma unroll
  for (int u = 0; u < 4; ++u)
    sum[u] = c0v[u] * f0 + c1v[u] * f1 + c2v[u] * f2 + c3v[u] * f3;

  const float l = redl[0][r] * f0 + redl[1][r] * f1
                + redl[2][r] * f2 + redl[3][r] * f3;
  const float linv = (l > 0.f) ? __builtin_amdgcn_rcpf(l) : 0.f;
  f32x4 o;
  #pragma unroll
  for (int u = 0; u < 4; ++u){
    float v = sum[u] * linv;
    o[u] = v > 0.f ? v : __expf(v) - 1.0f;     // ELU (alpha=1)
  }
  *(f32x4*)(out + ((size_t)(b * NN + i0 + r)) * FOUT + c4) = o;
}

extern "C" void kernel_launch(void* const* d_in, const int* in_sizes, int n_in,
                              void* d_out, int out_size, void* d_ws, size_t ws_size,
                              hipStream_t stream) {
  (void)in_sizes; (void)n_in; (void)out_size; (void)ws_size;
  const float* inp = (const float*)d_in[0];   // (16,1024,128) fp32
  const int*   adj = (const int*)d_in[1];     // (16,1024,1024) int32
  const float* W   = (const float*)d_in[2];   // (128,64) fp32
  const float* a   = (const float*)d_in[3];   // (128,1) fp32
  float* outp = (float*)d_out;                // (16,1024,64) fp32

  _Float16* hT = (_Float16*)d_ws;                      // 2 MB (hi only)
  float* s1 = (float*)(hT + (size_t)BB * 65536);       // 64 KB
  float* s2 = s1 + BB * NN;                            // 64 KB

  k_proj<<<BB * NN / 16, 256, 0, stream>>>(inp, W, a, hT, s1, s2);
  k_attn<<<BB * (NN / 16), 256, 0, stream>>>(adj, hT, s1, s2, outp);
}